// Round 5
// baseline (821.007 us; speedup 1.0000x reference)
//
#include <hip/hip_runtime.h>
#include <hip/hip_bf16.h>

// ---------------- problem constants ----------------
#define BB 8
#define SS 2000
#define IN_CH 120
#define NPTS 10000
#define IC 512
#define CATCH 248
#define CATPAD 256
#define MROWS 16000          // B*S
#define NSLICE 16
#define PTS_PER_SLICE 625

typedef __bf16 bf16x8 __attribute__((ext_vector_type(8)));
typedef float f32x4 __attribute__((ext_vector_type(4)));
typedef unsigned short u16x8 __attribute__((ext_vector_type(8)));

#define DEVI __device__ __forceinline__

DEVI unsigned short f2bf(float f) {
    __hip_bfloat16 h = __float2bfloat16(f);
    return __builtin_bit_cast(unsigned short, h);
}
DEVI float bf2f(unsigned short u) {
    unsigned int x = ((unsigned int)u) << 16;
    return __builtin_bit_cast(float, x);
}
DEVI float leaky(float x) { return x > 0.f ? x : 0.1f * x; }
DEVI unsigned int pk2(float a, float b) {
    return (unsigned int)f2bf(a) | ((unsigned int)f2bf(b) << 16);
}

// slab: [64 rows][512 k] bf16, 1024 B/row, 16B chunks XOR-swizzled by (row&7)
DEVI int slab_addr(int m, int ck) { return m * 1024 + ((ck ^ (m & 7)) << 4); }

// pack 4 consecutive-row values (this lane col n) into pair-exchanged dword
// stores; rows mbase..mbase+3. Verified numerics from R4 (absmax 5.86e-3).
DEVI void pack_store(char* smem, int mbase, int n, int fr,
                     float v0, float v1, float v2, float v3) {
    unsigned int p01 = pk2(v0, v1), p23 = pk2(v2, v3);
    unsigned int q01 = (unsigned int)__shfl_xor((int)p01, 1);
    unsigned int q23 = (unsigned int)__shfl_xor((int)p23, 1);
    int np = n & ~1;
    if (!(fr & 1)) {
        *(unsigned int*)(smem + slab_addr(mbase + 0, np >> 3) + (np & 7) * 2) =
            (p01 & 0xffffu) | ((q01 & 0xffffu) << 16);
        *(unsigned int*)(smem + slab_addr(mbase + 1, np >> 3) + (np & 7) * 2) =
            (p01 >> 16) | (q01 & 0xffff0000u);
    } else {
        *(unsigned int*)(smem + slab_addr(mbase + 2, np >> 3) + (np & 7) * 2) =
            (q23 & 0xffffu) | ((p23 & 0xffffu) << 16);
        *(unsigned int*)(smem + slab_addr(mbase + 3, np >> 3) + (np & 7) * 2) =
            (q23 >> 16) | (p23 & 0xffff0000u);
    }
}

// ---------------- workspace layout (bytes) ----------------
static const size_t OFF_FEATS  = 0;            // 8*128 f32
static const size_t OFF_PROJWT = 4096;         // 512*256 bf16
static const size_t OFF_RES0WT = 266240;       // 512*256 bf16
static const size_t OFF_RES1WT = 528384;       // 512*512 bf16
static const size_t OFF_LAYWT  = 1052672;      // 6*512*512 bf16
static const size_t OFF_PART   = 4198400;      // feats partials
static const size_t OFF_RG     = 12390400;     // r residual [16000][512] bf16

// ---------------- weight convert: f32 [L][K][N] -> bf16 [L][N][Kpad] ----
__global__ void wconv_k(const float* __restrict__ src, unsigned short* __restrict__ dst,
                        int K, int Kpad, int N, int total) {
    int idx = blockIdx.x * 256 + threadIdx.x;
    if (idx >= total) return;
    int k = idx % Kpad;
    int rem = idx / Kpad;
    int n = rem % N;
    int l = rem / N;
    float v = (k < K) ? src[((size_t)l * K + k) * N + n] : 0.f;
    dst[idx] = f2bf(v);
}

// ---------------- kernel regression stage 1 ----------------
__global__ __launch_bounds__(256) void feats_part_k(
    const float* __restrict__ gxy, const float* __restrict__ goff,
    const float* __restrict__ bws, const float* __restrict__ g0,
    const float* __restrict__ sloc, float* __restrict__ partial) {
    int bq = blockIdx.x;
    int b = bq >> 1, q = bq & 1;
    float qx = sloc[b * 4 + q * 2 + 0];
    float qy = sloc[b * 4 + q * 2 + 1];
    int i0 = blockIdx.y * PTS_PER_SLICE;
    int iend = i0 + PTS_PER_SLICE;
    float swt = 0.f;
    float sf[64];
#pragma unroll
    for (int c = 0; c < 64; c++) sf[c] = 0.f;
    for (int i = i0 + threadIdx.x; i < iend; i += 256) {
        float gx = gxy[i * 2 + 0] + tanhf(goff[i * 2 + 0]) * 0.1f;
        float gy = gxy[i * 2 + 1] + tanhf(goff[i * 2 + 1]) * 0.1f;
        float bw = fminf(fmaxf(bws[i], 0.1f), 0.5f);
        float dx = qx - gx, dy = qy - gy;
        float w = expf(-(dx * dx + dy * dy) / (bw * bw));
        swt += w;
#pragma unroll
        for (int c = 0; c < 64; c++) sf[c] += w * g0[(size_t)i * 64 + c];
    }
#pragma unroll
    for (int c = 0; c < 64; c++)
        for (int o = 32; o; o >>= 1) sf[c] += __shfl_down(sf[c], o);
    for (int o = 32; o; o >>= 1) swt += __shfl_down(swt, o);
    __shared__ float red[4][65];
    int lane = threadIdx.x & 63, wv = threadIdx.x >> 6;
    if (lane == 0) {
#pragma unroll
        for (int c = 0; c < 64; c++) red[wv][c] = sf[c];
        red[wv][64] = swt;
    }
    __syncthreads();
    size_t base = (size_t)(blockIdx.y * 16 + bq) * 72;
    if (threadIdx.x < 64) {
        int c = threadIdx.x;
        partial[base + c] = red[0][c] + red[1][c] + red[2][c] + red[3][c];
        if (c == 0)
            partial[base + 64] = red[0][64] + red[1][64] + red[2][64] + red[3][64];
    }
}

__global__ __launch_bounds__(128) void feats_reduce_k(
    const float* __restrict__ partial, float* __restrict__ feats) {
    int bq = blockIdx.x;
    __shared__ float s[66];
    int t = threadIdx.x;
    if (t < 65) {
        float acc = 0.f;
        for (int sl = 0; sl < NSLICE; ++sl)
            acc += partial[(size_t)(sl * 16 + bq) * 72 + t];
        s[t] = acc;
    }
    __syncthreads();
    if (t < 64) {
        int b = bq >> 1, q = bq & 1;
        feats[b * 128 + q * 64 + t] = s[t] / s[64];
    }
}

// ---------------- fused MLP chain ----------------
// block = 16 base rows (64 act rows), slab 64KB -> 2 blocks/CU.
// 4 waves, wave wv owns all 64 rows x cols wv*128..+127 (IM=4 frags, J=8 frags).
// Weights [n][Kpad] streamed to regs, depth-2 dbuf, per-wave K-rotation.
template <int IM, int J, int NK>
DEVI void gemm_phase(const char* smem, int arow0, const unsigned short* __restrict__ BT,
                     int Kpad, int wv, int lane, int rot, f32x4 (&acc)[IM][J]) {
    const int fr = lane & 15, c8 = lane >> 4;
#pragma unroll
    for (int i = 0; i < IM; i++)
#pragma unroll
        for (int j = 0; j < J; j++) acc[i][j] = (f32x4)0.f;
    const unsigned short* Bw = BT + (size_t)(wv * 128 + fr) * Kpad + (size_t)c8 * 8;
    const size_t jstep = (size_t)16 * Kpad;
    uint4 breg[2][J];
    {
        const int kc = rot;
#pragma unroll
        for (int j = 0; j < J; j++)
            breg[0][j] = *(const uint4*)(Bw + (size_t)j * jstep + (size_t)kc * 32);
    }
#pragma unroll
    for (int kt = 0; kt < NK; ++kt) {
        const int cur = kt & 1;
        if (kt + 1 < NK) {
            const int kcn = (rot + kt + 1) & (NK - 1);
#pragma unroll
            for (int j = 0; j < J; j++)
                breg[cur ^ 1][j] = *(const uint4*)(Bw + (size_t)j * jstep + (size_t)kcn * 32);
        }
        const int kc = (rot + kt) & (NK - 1);
        bf16x8 av[IM];
#pragma unroll
        for (int i = 0; i < IM; i++)
            av[i] = *(const bf16x8*)(smem + slab_addr(arow0 + i * 16 + fr, kc * 4 + c8));
#pragma unroll
        for (int i = 0; i < IM; i++)
#pragma unroll
            for (int j = 0; j < J; j++)
                acc[i][j] = __builtin_amdgcn_mfma_f32_16x16x32_bf16(
                    av[i], __builtin_bit_cast(bf16x8, breg[cur][j]), acc[i][j], 0, 0, 0);
    }
}

__global__ void __launch_bounds__(256, 2) fused_k(
    const float* __restrict__ feats, const float* __restrict__ inp,
    const unsigned short* __restrict__ projWT, const float* __restrict__ proj_b,
    const unsigned short* __restrict__ res0WT, const float* __restrict__ res_b0,
    const unsigned short* __restrict__ res1WT, const float* __restrict__ res_b1,
    const unsigned short* __restrict__ layWT, const float* __restrict__ layers_b,
    const float* __restrict__ channels, const float* __restrict__ outW,
    const float* __restrict__ outb, unsigned short* __restrict__ r_g,
    float* __restrict__ out) {
    __shared__ __align__(16) char smem[65536];
    const int tid = threadIdx.x;
    const int lane = tid & 63, wv = tid >> 6;     // 4 waves
    const int fr = lane & 15;
    const int hh = lane >> 4;                     // 0..3
    const size_t base0 = (size_t)blockIdx.x * 16; // base rows
    const int rotb = (wv + ((blockIdx.x & 1) << 1)) & 3;

    // ---- stage my_input -> slab rows 0..15, k 0..255 ----
    {
        int r = tid >> 4;                         // 0..15
        int cp = tid & 15;
        size_t mrow = base0 + r;
        int b = (int)(mrow / SS);
        const float* fb = feats + b * 128;
#pragma unroll
        for (int h = 0; h < 2; ++h) {
            int ck = cp * 2 + h;                  // 0..31
            unsigned int w[4];
#pragma unroll
            for (int p = 0; p < 4; ++p) {
                int k = ck * 8 + p * 2;
                float v0 = (k < 128) ? fb[k] : (k < CATCH ? inp[mrow * IN_CH + (k - 128)] : 0.f);
                int k1 = k + 1;
                float v1 = (k1 < 128) ? fb[k1] : (k1 < CATCH ? inp[mrow * IN_CH + (k1 - 128)] : 0.f);
                w[p] = pk2(v0, v1);
            }
            *(uint4*)(smem + slab_addr(r, ck)) = make_uint4(w[0], w[1], w[2], w[3]);
        }
    }
    __syncthreads();

    f32x4 acc1[1][8];

    // ---- res0: rows 0..15 @ res0WT -> leaky -> slab rows 16..31 (disjoint, no pre-barrier) ----
    gemm_phase<1, 8, 8>(smem, 0, res0WT, CATPAD, wv, lane, rotb * 2, acc1);
#pragma unroll
    for (int j = 0; j < 8; j++) {
        int n = wv * 128 + j * 16 + fr;
        float bn = res_b0[n];
        float v0 = leaky(acc1[0][j][0] + bn), v1 = leaky(acc1[0][j][1] + bn);
        float v2 = leaky(acc1[0][j][2] + bn), v3 = leaky(acc1[0][j][3] + bn);
        pack_store(smem, 16 + hh * 4, n, fr, v0, v1, v2, v3);
    }
    __syncthreads();

    // ---- res1: rows 16..31 @ res1WT + b1 -> r_g (global bf16) ----
    gemm_phase<1, 8, 16>(smem, 16, res1WT, IC, wv, lane, rotb * 4, acc1);
#pragma unroll
    for (int j = 0; j < 8; j++) {
        int n = wv * 128 + j * 16 + fr;
        float bn = res_b1[n];
#pragma unroll
        for (int rg = 0; rg < 4; rg++) {
            int mb = hh * 4 + rg;
            r_g[(base0 + mb) * IC + n] = f2bf(acc1[0][j][rg] + bn);
        }
    }

    // ---- proj: rows 0..15 @ projWT; expand x4 dirs + ch0, leaky -> slab rows 0..63 ----
    gemm_phase<1, 8, 8>(smem, 0, projWT, CATPAD, wv, lane, rotb * 2, acc1);
    __syncthreads();   // all waves done reading rows 0..31 before overwrite
#pragma unroll
    for (int j = 0; j < 8; j++) {
        int n = wv * 128 + j * 16 + fr;
        float bn = proj_b[n];
        float ch[4];
#pragma unroll
        for (int d = 0; d < 4; d++) ch[d] = channels[d * 512 + n];
#pragma unroll
        for (int rg = 0; rg < 4; rg++) {
            int mb = hh * 4 + rg;
            float vb = acc1[0][j][rg] + bn;
            pack_store(smem, mb * 4, n, fr,
                       leaky(vb + ch[0]), leaky(vb + ch[1]),
                       leaky(vb + ch[2]), leaky(vb + ch[3]));
        }
    }
    __syncthreads();

    // ---- 6 layers ----
    f32x4 acc[4][8];
    for (int l = 0; l < 6; ++l) {
        gemm_phase<4, 8, 16>(smem, 0, layWT + (size_t)l * 262144, IC, wv, lane, rotb * 4, acc);
        __syncthreads();   // all reads done before overwrite
        const float* bias = layers_b + l * 512;
        const float* chan = channels + (l + 1) * 2048;
        const bool use_r = (l == 2);
        const bool do_lk = (l != 5);
#pragma unroll
        for (int i = 0; i < 4; i++) {
#pragma unroll
            for (int j = 0; j < 8; j++) {
                int n = wv * 128 + j * 16 + fr;
                float bn = bias[n];
                float rv = 0.f;
                if (use_r) rv = bf2f(r_g[(base0 + i * 4 + hh) * IC + n]);
                float v[4];
#pragma unroll
                for (int rg = 0; rg < 4; rg++) {
                    float u = acc[i][j][rg] + bn + chan[rg * 512 + n] + rv;
                    v[rg] = do_lk ? leaky(u) : u;
                }
                pack_store(smem, i * 16 + hh * 4, n, fr, v[0], v[1], v[2], v[3]);
            }
        }
        __syncthreads();
    }

    // ---- final: out[gm][2] = slab_row @ outW + outb ----
    {
        int m = tid >> 2;                 // 0..63
        int q = tid & 3;
        float s0 = 0.f, s1 = 0.f;
#pragma unroll
        for (int c = 0; c < 16; ++c) {
            int ck = q * 16 + c;
            u16x8 a = *(const u16x8*)(smem + slab_addr(m, ck));
#pragma unroll
            for (int e = 0; e < 8; ++e) {
                int k = ck * 8 + e;
                float av = bf2f(a[e]);
                float2 wp = *(const float2*)&outW[k * 2];
                s0 = fmaf(av, wp.x, s0);
                s1 = fmaf(av, wp.y, s1);
            }
        }
        s0 += __shfl_down(s0, 2); s0 += __shfl_down(s0, 1);
        s1 += __shfl_down(s1, 2); s1 += __shfl_down(s1, 1);
        if (q == 0) {
            size_t gm = (size_t)blockIdx.x * 64 + m;
            out[gm * 2 + 0] = s0 + outb[0];
            out[gm * 2 + 1] = s1 + outb[1];
        }
    }
}

extern "C" void kernel_launch(void* const* d_in, const int* in_sizes, int n_in,
                              void* d_out, int out_size, void* d_ws, size_t ws_size,
                              hipStream_t stream) {
    const float* input_stuff = (const float*)d_in[0];
    const float* sound_loc   = (const float*)d_in[1];
    const float* grid_xy     = (const float*)d_in[2];
    const float* xy_offset   = (const float*)d_in[3];
    const float* bandwidths  = (const float*)d_in[4];
    const float* grid_0      = (const float*)d_in[5];
    const float* proj_W      = (const float*)d_in[6];
    const float* proj_b      = (const float*)d_in[7];
    const float* res_W0      = (const float*)d_in[8];
    const float* res_b0      = (const float*)d_in[9];
    const float* res_W1      = (const float*)d_in[10];
    const float* res_b1      = (const float*)d_in[11];
    const float* layers_W    = (const float*)d_in[12];
    const float* layers_b    = (const float*)d_in[13];
    const float* channels    = (const float*)d_in[14];
    const float* out_W       = (const float*)d_in[15];
    const float* out_b       = (const float*)d_in[16];

    char* ws = (char*)d_ws;
    float* feats            = (float*)(ws + OFF_FEATS);
    unsigned short* projWT  = (unsigned short*)(ws + OFF_PROJWT);
    unsigned short* res0WT  = (unsigned short*)(ws + OFF_RES0WT);
    unsigned short* res1WT  = (unsigned short*)(ws + OFF_RES1WT);
    unsigned short* layWT   = (unsigned short*)(ws + OFF_LAYWT);
    float* partial          = (float*)(ws + OFF_PART);
    unsigned short* r_g     = (unsigned short*)(ws + OFF_RG);

    wconv_k<<<(512 * 256 + 255) / 256, 256, 0, stream>>>(proj_W, projWT, CATCH, CATPAD, IC, 512 * 256);
    wconv_k<<<(512 * 256 + 255) / 256, 256, 0, stream>>>(res_W0, res0WT, CATCH, CATPAD, IC, 512 * 256);
    wconv_k<<<(512 * 512 + 255) / 256, 256, 0, stream>>>(res_W1, res1WT, IC, IC, IC, 512 * 512);
    wconv_k<<<(6 * 512 * 512 + 255) / 256, 256, 0, stream>>>(layers_W, layWT, IC, IC, IC, 6 * 512 * 512);

    feats_part_k<<<dim3(16, NSLICE), 256, 0, stream>>>(grid_xy, xy_offset, bandwidths, grid_0, sound_loc, partial);
    feats_reduce_k<<<16, 128, 0, stream>>>(partial, feats);

    fused_k<<<1000, 256, 0, stream>>>(
        feats, input_stuff, projWT, proj_b, res0WT, res_b0, res1WT, res_b1,
        layWT, layers_b, channels, out_W, out_b, r_g, (float*)d_out);
}

// Round 6
// 596.712 us; speedup vs baseline: 1.3759x; 1.3759x over previous
//
#include <hip/hip_runtime.h>
#include <hip/hip_bf16.h>

// ---------------- problem constants ----------------
#define BB 8
#define SS 2000
#define IN_CH 120
#define NPTS 10000
#define IC 512
#define CATCH 248
#define CATPAD 256
#define MROWS 16000          // B*S
#define MROWS4 64000         // B*S*DIRS
#define NSLICE 16
#define PTS_PER_SLICE 625

typedef __bf16 bf16x8 __attribute__((ext_vector_type(8)));
typedef float f32x4 __attribute__((ext_vector_type(4)));

#define DEVI __device__ __forceinline__

DEVI unsigned short f2bf(float f) {
    __hip_bfloat16 h = __float2bfloat16(f);
    return __builtin_bit_cast(unsigned short, h);
}
DEVI float bf2f(unsigned short u) {
    unsigned int x = ((unsigned int)u) << 16;
    return __builtin_bit_cast(float, x);
}
DEVI float leaky(float x) { return x > 0.f ? x : 0.1f * x; }

DEVI void gload16(const void* g, void* l) {
    __builtin_amdgcn_global_load_lds(
        (const unsigned int __attribute__((address_space(1)))*)g,
        (unsigned int __attribute__((address_space(3)))*)l, 16, 0, 0);
}

// XCD-chunked bijective swizzle (m204)
DEVI int xcd_swizzle() {
    int nwg = (int)gridDim.x;
    int orig = (int)blockIdx.x;
    int q = nwg >> 3, r = nwg & 7;
    int xcd = orig & 7, pos = orig >> 3;
    int base = xcd < r ? xcd * (q + 1) : r * (q + 1) + (xcd - r) * q;
    return base + pos;
}

// ---------------- workspace layout (bytes) ----------------
static const size_t OFF_FEATS  = 0;            // 8*128 f32
static const size_t OFF_PROJWT = 4096;         // 512*256 bf16
static const size_t OFF_RES0WT = 266240;       // 512*256 bf16
static const size_t OFF_RES1WT = 528384;       // 512*512 bf16
static const size_t OFF_LAYWT  = 1052672;      // 6*512*512 bf16
static const size_t OFF_MYIN   = 4198400;      // 16000*256 bf16
static const size_t OFF_R0     = 12390400;     // 16000*512 bf16
static const size_t OFF_R      = 28774400;     // 16000*512 bf16
static const size_t OFF_A0     = 45158400;     // 64000*512 bf16
static const size_t OFF_A1     = 110694400;    // 64000*512 bf16
// feats partials overlap A0 (consumed before proj writes A0)

// ---------------- weight convert: f32 [L][K][N] -> bf16 [L][N][Kpad] ----
__global__ void wconv_k(const float* __restrict__ src, unsigned short* __restrict__ dst,
                        int K, int Kpad, int N, int total) {
    int idx = blockIdx.x * 256 + threadIdx.x;
    if (idx >= total) return;
    int k = idx % Kpad;
    int rem = idx / Kpad;
    int n = rem % N;
    int l = rem / N;
    float v = (k < K) ? src[((size_t)l * K + k) * N + n] : 0.f;
    dst[idx] = f2bf(v);
}

// ---------------- kernel regression stage 1 ----------------
__global__ __launch_bounds__(256) void feats_part_k(
    const float* __restrict__ gxy, const float* __restrict__ goff,
    const float* __restrict__ bws, const float* __restrict__ g0,
    const float* __restrict__ sloc, float* __restrict__ partial) {
    int bq = blockIdx.x;
    int b = bq >> 1, q = bq & 1;
    float qx = sloc[b * 4 + q * 2 + 0];
    float qy = sloc[b * 4 + q * 2 + 1];
    int i0 = blockIdx.y * PTS_PER_SLICE;
    int iend = i0 + PTS_PER_SLICE;
    float swt = 0.f;
    float sf[64];
#pragma unroll
    for (int c = 0; c < 64; c++) sf[c] = 0.f;
    for (int i = i0 + threadIdx.x; i < iend; i += 256) {
        float gx = gxy[i * 2 + 0] + tanhf(goff[i * 2 + 0]) * 0.1f;
        float gy = gxy[i * 2 + 1] + tanhf(goff[i * 2 + 1]) * 0.1f;
        float bw = fminf(fmaxf(bws[i], 0.1f), 0.5f);
        float dx = qx - gx, dy = qy - gy;
        float w = expf(-(dx * dx + dy * dy) / (bw * bw));
        swt += w;
#pragma unroll
        for (int c = 0; c < 64; c++) sf[c] += w * g0[(size_t)i * 64 + c];
    }
#pragma unroll
    for (int c = 0; c < 64; c++)
        for (int o = 32; o; o >>= 1) sf[c] += __shfl_down(sf[c], o);
    for (int o = 32; o; o >>= 1) swt += __shfl_down(swt, o);
    __shared__ float red[4][65];
    int lane = threadIdx.x & 63, wv = threadIdx.x >> 6;
    if (lane == 0) {
#pragma unroll
        for (int c = 0; c < 64; c++) red[wv][c] = sf[c];
        red[wv][64] = swt;
    }
    __syncthreads();
    size_t base = (size_t)(blockIdx.y * 16 + bq) * 72;
    if (threadIdx.x < 64) {
        int c = threadIdx.x;
        partial[base + c] = red[0][c] + red[1][c] + red[2][c] + red[3][c];
        if (c == 0)
            partial[base + 64] = red[0][64] + red[1][64] + red[2][64] + red[3][64];
    }
}

__global__ __launch_bounds__(128) void feats_reduce_k(
    const float* __restrict__ partial, float* __restrict__ feats) {
    int bq = blockIdx.x;
    __shared__ float s[66];
    int t = threadIdx.x;
    if (t < 65) {
        float acc = 0.f;
        for (int sl = 0; sl < NSLICE; ++sl)
            acc += partial[(size_t)(sl * 16 + bq) * 72 + t];
        s[t] = acc;
    }
    __syncthreads();
    if (t < 64) {
        int b = bq >> 1, q = bq & 1;
        feats[b * 128 + q * 64 + t] = s[t] / s[64];
    }
}

// ---------------- build my_input bf16 [16000][256] ----------------
__global__ void build_k(const float* __restrict__ feats, const float* __restrict__ inp,
                        unsigned short* __restrict__ dst) {
    int idx = blockIdx.x * 256 + threadIdx.x;
    int c = idx & 255;
    int m = idx >> 8;
    int b = m / SS;
    float v;
    if (c < 128) v = feats[b * 128 + c];
    else if (c < CATCH) v = inp[(size_t)m * IN_CH + (c - 128)];
    else v = 0.f;
    dst[idx] = f2bf(v);
}

// ---------------- MFMA GEMM: 128x128 tile, BK=32, k-chunked LDS ----------------
// LDS per tile: [4 kchunk][128 row][8 k] bf16 = 8KB; conflict-free b128 reads
// (row stride 16B). Double-buffered A+B = 32KB total -> 4 blocks/CU.
// EPI: 0=PROJ(expand x4 +ch0, leaky) 1=LAYER 2=LAYER+RES 3=LAYER_LAST
//      4=SIMPLE+leaky 5=SIMPLE
template <int EPI>
__global__ __launch_bounds__(256, 4) void gemm_k(
    const unsigned short* __restrict__ A, const unsigned short* __restrict__ BT,
    unsigned short* __restrict__ out, int K,
    const float* __restrict__ bias, const float* __restrict__ chan,
    const unsigned short* __restrict__ resid) {
    __shared__ __align__(16) unsigned short lds[2][2][4096];  // [buf][A/B][4][128][8]
    const int tid = threadIdx.x;
    const int lane = tid & 63, wv = tid >> 6;
    const int wm = wv >> 1, wn = wv & 1;
    const int c8 = lane >> 4;                   // k-chunk 0..3
    const int fr = lane & 15;

    const int swz = xcd_swizzle();
    const int bx = swz >> 2, by = swz & 3;

    // fragment LDS offsets (ushort units): chunk c8, row ra -> c8*1024 + ra*8
    int aoff[4], boff[4];
#pragma unroll
    for (int i = 0; i < 4; i++) {
        aoff[i] = c8 * 1024 + (wm * 64 + i * 16 + fr) * 8;
        boff[i] = c8 * 1024 + (wn * 64 + i * 16 + fr) * 8;
    }
    // staging: 2 issues of 16B per thread per tile per matrix; linear LDS dest
    // byte o = t*4096 + tid*16 -> chunk = o>>11, row = (o>>4)&127
    int ldso[2];
    size_t src[2];
    const unsigned short* Ab = A + (size_t)bx * 128 * K;
    const unsigned short* Bb = BT + (size_t)by * 128 * K;
#pragma unroll
    for (int t = 0; t < 2; t++) {
        int o = t * 4096 + tid * 16;
        int ck = o >> 11;
        int r = (o >> 4) & 127;
        ldso[t] = o >> 1;
        src[t] = (size_t)r * K + ck * 8;
    }

    f32x4 acc[4][4];
#pragma unroll
    for (int i = 0; i < 4; i++)
#pragma unroll
        for (int j = 0; j < 4; j++) acc[i][j] = (f32x4)0.f;

    const int nK = K >> 5;
    // prologue: stage tile 0 into buf 0
#pragma unroll
    for (int t = 0; t < 2; t++) gload16(Ab + src[t], &lds[0][0][ldso[t]]);
#pragma unroll
    for (int t = 0; t < 2; t++) gload16(Bb + src[t], &lds[0][1][ldso[t]]);
    asm volatile("s_waitcnt vmcnt(0)" ::: "memory");
    __builtin_amdgcn_s_barrier();
    __builtin_amdgcn_sched_barrier(0);

    int buf = 0;
    for (int kt = 0; kt < nK; ++kt) {
        if (kt + 1 < nK) {
            const int k1 = (kt + 1) << 5;
#pragma unroll
            for (int t = 0; t < 2; t++) gload16(Ab + src[t] + k1, &lds[buf ^ 1][0][ldso[t]]);
#pragma unroll
            for (int t = 0; t < 2; t++) gload16(Bb + src[t] + k1, &lds[buf ^ 1][1][ldso[t]]);
        }
        bf16x8 av[4], bv[4];
#pragma unroll
        for (int i = 0; i < 4; i++) av[i] = *(const bf16x8*)&lds[buf][0][aoff[i]];
#pragma unroll
        for (int j = 0; j < 4; j++) bv[j] = *(const bf16x8*)&lds[buf][1][boff[j]];
#pragma unroll
        for (int i = 0; i < 4; i++)
#pragma unroll
            for (int j = 0; j < 4; j++)
                acc[i][j] = __builtin_amdgcn_mfma_f32_16x16x32_bf16(av[i], bv[j], acc[i][j], 0, 0, 0);
        if (kt + 1 < nK) {
            asm volatile("s_waitcnt vmcnt(0)" ::: "memory");
            __builtin_amdgcn_s_barrier();
            __builtin_amdgcn_sched_barrier(0);
        }
        buf ^= 1;
    }

    // epilogue: C/D frag: col = lane&15, row = (lane>>4)*4 + reg   [m89-verified]
    const int rbase = (lane >> 4) << 2;
    const size_t m0 = (size_t)bx * 128;
    const int n0 = by * 128;
#pragma unroll
    for (int i = 0; i < 4; i++) {
#pragma unroll
        for (int j = 0; j < 4; j++) {
#pragma unroll
            for (int rg = 0; rg < 4; ++rg) {
                size_t m = m0 + wm * 64 + i * 16 + rbase + rg;
                int n = n0 + wn * 64 + j * 16 + fr;
                float v = acc[i][j][rg];
                if constexpr (EPI == 0) {
                    float v0 = v + bias[n];
#pragma unroll
                    for (int d = 0; d < 4; ++d) {
                        float u = v0 + chan[d * 512 + n];
                        out[(m * 4 + d) * 512 + n] = f2bf(leaky(u));
                    }
                } else if constexpr (EPI == 1 || EPI == 2 || EPI == 3) {
                    int d = (int)(m & 3);
                    float u = v + bias[n] + chan[d * 512 + n];
                    if constexpr (EPI == 2) u += bf2f(resid[(m >> 2) * 512 + n]);
                    out[m * 512 + n] = f2bf(EPI == 3 ? u : leaky(u));
                } else {
                    float u = v + bias[n];
                    out[m * 512 + n] = f2bf(EPI == 4 ? leaky(u) : u);
                }
            }
        }
    }
}

// ---------------- final: out[64000][2] ----------------
__global__ __launch_bounds__(256) void final_k(
    const unsigned short* __restrict__ A, const float* __restrict__ outW,
    const float* __restrict__ outb, float* __restrict__ out) {
    int gw = blockIdx.x * 4 + (threadIdx.x >> 6);
    int lane = threadIdx.x & 63;
    const unsigned short* row = A + (size_t)gw * 512;
    uint4 bits = *(const uint4*)(row + lane * 8);
    unsigned int ww[4] = {bits.x, bits.y, bits.z, bits.w};
    float s0 = 0.f, s1 = 0.f;
#pragma unroll
    for (int j = 0; j < 8; j++) {
        unsigned short u = (unsigned short)((ww[j >> 1] >> ((j & 1) * 16)) & 0xffff);
        float a = bf2f(u);
        int k = lane * 8 + j;
        s0 = fmaf(a, outW[k * 2 + 0], s0);
        s1 = fmaf(a, outW[k * 2 + 1], s1);
    }
    for (int o = 32; o; o >>= 1) {
        s0 += __shfl_down(s0, o);
        s1 += __shfl_down(s1, o);
    }
    if (lane == 0) {
        out[(size_t)gw * 2 + 0] = s0 + outb[0];
        out[(size_t)gw * 2 + 1] = s1 + outb[1];
    }
}

extern "C" void kernel_launch(void* const* d_in, const int* in_sizes, int n_in,
                              void* d_out, int out_size, void* d_ws, size_t ws_size,
                              hipStream_t stream) {
    const float* input_stuff = (const float*)d_in[0];
    const float* sound_loc   = (const float*)d_in[1];
    const float* grid_xy     = (const float*)d_in[2];
    const float* xy_offset   = (const float*)d_in[3];
    const float* bandwidths  = (const float*)d_in[4];
    const float* grid_0      = (const float*)d_in[5];
    const float* proj_W      = (const float*)d_in[6];
    const float* proj_b      = (const float*)d_in[7];
    const float* res_W0      = (const float*)d_in[8];
    const float* res_b0      = (const float*)d_in[9];
    const float* res_W1      = (const float*)d_in[10];
    const float* res_b1      = (const float*)d_in[11];
    const float* layers_W    = (const float*)d_in[12];
    const float* layers_b    = (const float*)d_in[13];
    const float* channels    = (const float*)d_in[14];
    const float* out_W       = (const float*)d_in[15];
    const float* out_b       = (const float*)d_in[16];

    char* ws = (char*)d_ws;
    float* feats            = (float*)(ws + OFF_FEATS);
    unsigned short* projWT  = (unsigned short*)(ws + OFF_PROJWT);
    unsigned short* res0WT  = (unsigned short*)(ws + OFF_RES0WT);
    unsigned short* res1WT  = (unsigned short*)(ws + OFF_RES1WT);
    unsigned short* layWT   = (unsigned short*)(ws + OFF_LAYWT);
    unsigned short* myin    = (unsigned short*)(ws + OFF_MYIN);
    unsigned short* R0      = (unsigned short*)(ws + OFF_R0);
    unsigned short* Rb      = (unsigned short*)(ws + OFF_R);
    unsigned short* A0      = (unsigned short*)(ws + OFF_A0);
    unsigned short* A1      = (unsigned short*)(ws + OFF_A1);
    float* partial          = (float*)(ws + OFF_A0);

    wconv_k<<<(512 * 256 + 255) / 256, 256, 0, stream>>>(proj_W, projWT, CATCH, CATPAD, IC, 512 * 256);
    wconv_k<<<(512 * 256 + 255) / 256, 256, 0, stream>>>(res_W0, res0WT, CATCH, CATPAD, IC, 512 * 256);
    wconv_k<<<(512 * 512 + 255) / 256, 256, 0, stream>>>(res_W1, res1WT, IC, IC, IC, 512 * 512);
    wconv_k<<<(6 * 512 * 512 + 255) / 256, 256, 0, stream>>>(layers_W, layWT, IC, IC, IC, 6 * 512 * 512);

    feats_part_k<<<dim3(16, NSLICE), 256, 0, stream>>>(grid_xy, xy_offset, bandwidths, grid_0, sound_loc, partial);
    feats_reduce_k<<<16, 128, 0, stream>>>(partial, feats);
    build_k<<<MROWS, 256, 0, stream>>>(feats, input_stuff, myin);

    // proj (+channels[0], leaky, expand x4) -> A0
    gemm_k<0><<<500, 256, 0, stream>>>(myin, projWT, A0, CATPAD, proj_b, channels, nullptr);
    // residual branch
    gemm_k<4><<<500, 256, 0, stream>>>(myin, res0WT, R0, CATPAD, res_b0, nullptr, nullptr);
    gemm_k<5><<<500, 256, 0, stream>>>(R0, res1WT, Rb, IC, res_b1, nullptr, nullptr);
    // 6 layers, ping-pong A0/A1; residual at k==2; k==5 last (no leaky)
    gemm_k<1><<<2000, 256, 0, stream>>>(A0, layWT + 0 * 262144, A1, IC, layers_b + 0 * 512, channels + 1 * 2048, nullptr);
    gemm_k<1><<<2000, 256, 0, stream>>>(A1, layWT + 1 * 262144, A0, IC, layers_b + 1 * 512, channels + 2 * 2048, nullptr);
    gemm_k<2><<<2000, 256, 0, stream>>>(A0, layWT + 2 * 262144, A1, IC, layers_b + 2 * 512, channels + 3 * 2048, Rb);
    gemm_k<1><<<2000, 256, 0, stream>>>(A1, layWT + 3 * 262144, A0, IC, layers_b + 3 * 512, channels + 4 * 2048, nullptr);
    gemm_k<1><<<2000, 256, 0, stream>>>(A0, layWT + 4 * 262144, A1, IC, layers_b + 4 * 512, channels + 5 * 2048, nullptr);
    gemm_k<3><<<2000, 256, 0, stream>>>(A1, layWT + 5 * 262144, A0, IC, layers_b + 5 * 512, channels + 6 * 2048, nullptr);

    final_k<<<MROWS, 256, 0, stream>>>(A0, out_W, out_b, (float*)d_out);
}

// Round 7
// 581.218 us; speedup vs baseline: 1.4126x; 1.0267x over previous
//
#include <hip/hip_runtime.h>
#include <hip/hip_bf16.h>

// ---------------- problem constants ----------------
#define BB 8
#define SS 2000
#define IN_CH 120
#define NPTS 10000
#define IC 512
#define CATCH 248
#define CATPAD 256
#define MROWS 16000          // B*S
#define MROWS4 64000         // B*S*DIRS
#define NSLICE 16
#define PTS_PER_SLICE 625

typedef __bf16 bf16x8 __attribute__((ext_vector_type(8)));
typedef float f32x4 __attribute__((ext_vector_type(4)));

#define DEVI __device__ __forceinline__

DEVI unsigned short f2bf(float f) {
    __hip_bfloat16 h = __float2bfloat16(f);
    return __builtin_bit_cast(unsigned short, h);
}
DEVI float bf2f(unsigned short u) {
    unsigned int x = ((unsigned int)u) << 16;
    return __builtin_bit_cast(float, x);
}
DEVI float leaky(float x) { return x > 0.f ? x : 0.1f * x; }

DEVI void gload16(const void* g, void* l) {
    __builtin_amdgcn_global_load_lds(
        (const unsigned int __attribute__((address_space(1)))*)g,
        (unsigned int __attribute__((address_space(3)))*)l, 16, 0, 0);
}

// XCD-chunked bijective swizzle (m204)
DEVI int xcd_swizzle() {
    int nwg = (int)gridDim.x;
    int orig = (int)blockIdx.x;
    int q = nwg >> 3, r = nwg & 7;
    int xcd = orig & 7, pos = orig >> 3;
    int base = xcd < r ? xcd * (q + 1) : r * (q + 1) + (xcd - r) * q;
    return base + pos;
}

// ---------------- workspace layout (bytes) ----------------
static const size_t OFF_FEATS  = 0;            // 8*128 f32
static const size_t OFF_PROJWT = 4096;         // 512*256 bf16
static const size_t OFF_RES0WT = 266240;       // 512*256 bf16
static const size_t OFF_RES1WT = 528384;       // 512*512 bf16
static const size_t OFF_LAYWT  = 1052672;      // 6*512*512 bf16
static const size_t OFF_MYIN   = 4198400;      // 16000*256 bf16
static const size_t OFF_R0     = 12390400;     // 16000*512 bf16
static const size_t OFF_R      = 28774400;     // 16000*512 bf16
static const size_t OFF_A0     = 45158400;     // 64000*512 bf16
static const size_t OFF_A1     = 110694400;    // 64000*512 bf16
// feats partials overlap A0 (consumed before proj writes A0)

// ---------------- weight convert: f32 [L][K][N] -> bf16 [L][N][Kpad] ----
__global__ void wconv_k(const float* __restrict__ src, unsigned short* __restrict__ dst,
                        int K, int Kpad, int N, int total) {
    int idx = blockIdx.x * 256 + threadIdx.x;
    if (idx >= total) return;
    int k = idx % Kpad;
    int rem = idx / Kpad;
    int n = rem % N;
    int l = rem / N;
    float v = (k < K) ? src[((size_t)l * K + k) * N + n] : 0.f;
    dst[idx] = f2bf(v);
}

// ---------------- kernel regression stage 1 ----------------
__global__ __launch_bounds__(256) void feats_part_k(
    const float* __restrict__ gxy, const float* __restrict__ goff,
    const float* __restrict__ bws, const float* __restrict__ g0,
    const float* __restrict__ sloc, float* __restrict__ partial) {
    int bq = blockIdx.x;
    int b = bq >> 1, q = bq & 1;
    float qx = sloc[b * 4 + q * 2 + 0];
    float qy = sloc[b * 4 + q * 2 + 1];
    int i0 = blockIdx.y * PTS_PER_SLICE;
    int iend = i0 + PTS_PER_SLICE;
    float swt = 0.f;
    float sf[64];
#pragma unroll
    for (int c = 0; c < 64; c++) sf[c] = 0.f;
    for (int i = i0 + threadIdx.x; i < iend; i += 256) {
        float gx = gxy[i * 2 + 0] + tanhf(goff[i * 2 + 0]) * 0.1f;
        float gy = gxy[i * 2 + 1] + tanhf(goff[i * 2 + 1]) * 0.1f;
        float bw = fminf(fmaxf(bws[i], 0.1f), 0.5f);
        float dx = qx - gx, dy = qy - gy;
        float w = expf(-(dx * dx + dy * dy) / (bw * bw));
        swt += w;
#pragma unroll
        for (int c = 0; c < 64; c++) sf[c] += w * g0[(size_t)i * 64 + c];
    }
#pragma unroll
    for (int c = 0; c < 64; c++)
        for (int o = 32; o; o >>= 1) sf[c] += __shfl_down(sf[c], o);
    for (int o = 32; o; o >>= 1) swt += __shfl_down(swt, o);
    __shared__ float red[4][65];
    int lane = threadIdx.x & 63, wv = threadIdx.x >> 6;
    if (lane == 0) {
#pragma unroll
        for (int c = 0; c < 64; c++) red[wv][c] = sf[c];
        red[wv][64] = swt;
    }
    __syncthreads();
    size_t base = (size_t)(blockIdx.y * 16 + bq) * 72;
    if (threadIdx.x < 64) {
        int c = threadIdx.x;
        partial[base + c] = red[0][c] + red[1][c] + red[2][c] + red[3][c];
        if (c == 0)
            partial[base + 64] = red[0][64] + red[1][64] + red[2][64] + red[3][64];
    }
}

__global__ __launch_bounds__(128) void feats_reduce_k(
    const float* __restrict__ partial, float* __restrict__ feats) {
    int bq = blockIdx.x;
    __shared__ float s[66];
    int t = threadIdx.x;
    if (t < 65) {
        float acc = 0.f;
        for (int sl = 0; sl < NSLICE; ++sl)
            acc += partial[(size_t)(sl * 16 + bq) * 72 + t];
        s[t] = acc;
    }
    __syncthreads();
    if (t < 64) {
        int b = bq >> 1, q = bq & 1;
        feats[b * 128 + q * 64 + t] = s[t] / s[64];
    }
}

// ---------------- build my_input bf16 [16000][256] ----------------
__global__ void build_k(const float* __restrict__ feats, const float* __restrict__ inp,
                        unsigned short* __restrict__ dst) {
    int idx = blockIdx.x * 256 + threadIdx.x;
    int c = idx & 255;
    int m = idx >> 8;
    int b = m / SS;
    float v;
    if (c < 128) v = feats[b * 128 + c];
    else if (c < CATCH) v = inp[(size_t)m * IN_CH + (c - 128)];
    else v = 0.f;
    dst[idx] = f2bf(v);
}

// ---------------- MFMA GEMM: 128x128 tile, BK=32, 3-stage counted-vmcnt pipeline ----
// LDS tile [4 kchunk][128 row][8 k] bf16 = 8KB/matrix, conflict-free b128 reads.
// 3 buffers x (A+B) = 48KB -> 3 blocks/CU. Depth-2 prefetch: stage t+2 before
// compute t; s_waitcnt vmcnt(4) keeps t+2's 4 loads in flight across the barrier.
// EPI: 0=PROJ(expand x4 +ch0, leaky) 1=LAYER 2=LAYER+RES 3=LAYER_LAST
//      4=SIMPLE+leaky 5=SIMPLE
template <int EPI>
__global__ __launch_bounds__(256) void gemm_k(
    const unsigned short* __restrict__ A, const unsigned short* __restrict__ BT,
    unsigned short* __restrict__ out, int K,
    const float* __restrict__ bias, const float* __restrict__ chan,
    const unsigned short* __restrict__ resid) {
    __shared__ __align__(16) unsigned short lds[3][2][4096];  // [buf][A/B][4][128][8]
    const int tid = threadIdx.x;
    const int lane = tid & 63, wv = tid >> 6;
    const int wm = wv >> 1, wn = wv & 1;
    const int c8 = lane >> 4;                   // k-chunk 0..3
    const int fr = lane & 15;

    const int swz = xcd_swizzle();
    const int bx = swz >> 2, by = swz & 3;

    // fragment LDS offsets (ushort units): chunk c8, row ra -> c8*1024 + ra*8
    int aoff[4], boff[4];
#pragma unroll
    for (int i = 0; i < 4; i++) {
        aoff[i] = c8 * 1024 + (wm * 64 + i * 16 + fr) * 8;
        boff[i] = c8 * 1024 + (wn * 64 + i * 16 + fr) * 8;
    }
    // staging: 2 issues of 16B per thread per matrix; linear LDS dest
    int ldso[2];
    size_t src[2];
    const unsigned short* Ab = A + (size_t)bx * 128 * K;
    const unsigned short* Bb = BT + (size_t)by * 128 * K;
#pragma unroll
    for (int t = 0; t < 2; t++) {
        int o = t * 4096 + tid * 16;
        int ck = o >> 11;
        int r = (o >> 4) & 127;
        ldso[t] = o >> 1;
        src[t] = (size_t)r * K + ck * 8;
    }

#define STAGE(kt, bf)                                                          \
    {                                                                          \
        const int koff = (kt) << 5;                                            \
        _Pragma("unroll") for (int t = 0; t < 2; t++)                          \
            gload16(Ab + src[t] + koff, &lds[bf][0][ldso[t]]);                 \
        _Pragma("unroll") for (int t = 0; t < 2; t++)                          \
            gload16(Bb + src[t] + koff, &lds[bf][1][ldso[t]]);                 \
    }

    f32x4 acc[4][4];
#pragma unroll
    for (int i = 0; i < 4; i++)
#pragma unroll
        for (int j = 0; j < 4; j++) acc[i][j] = (f32x4)0.f;

    const int nK = K >> 5;                      // 8 or 16, always >= 2
    // prologue: stage t0, t1; wait t0 (t1 stays in flight)
    STAGE(0, 0);
    STAGE(1, 1);
    asm volatile("s_waitcnt vmcnt(4)" ::: "memory");
    __builtin_amdgcn_s_barrier();
    __builtin_amdgcn_sched_barrier(0);

    int cur = 0;
    for (int kt = 0; kt < nK; ++kt) {
        const int nxt2 = cur + 2 >= 3 ? cur - 1 : cur + 2;
        if (kt + 2 < nK) STAGE(kt + 2, nxt2);
        bf16x8 av[4], bv[4];
#pragma unroll
        for (int i = 0; i < 4; i++) av[i] = *(const bf16x8*)&lds[cur][0][aoff[i]];
#pragma unroll
        for (int j = 0; j < 4; j++) bv[j] = *(const bf16x8*)&lds[cur][1][boff[j]];
#pragma unroll
        for (int i = 0; i < 4; i++)
#pragma unroll
            for (int j = 0; j < 4; j++)
                acc[i][j] = __builtin_amdgcn_mfma_f32_16x16x32_bf16(av[i], bv[j], acc[i][j], 0, 0, 0);
        if (kt + 1 < nK) {
            if (kt + 2 < nK) {
                asm volatile("s_waitcnt vmcnt(4)" ::: "memory");  // t+1 done, t+2 flying
            } else {
                asm volatile("s_waitcnt vmcnt(0)" ::: "memory");  // tail
            }
            __builtin_amdgcn_s_barrier();
            __builtin_amdgcn_sched_barrier(0);
        }
        cur = cur + 1 >= 3 ? 0 : cur + 1;
    }
#undef STAGE

    // epilogue: C/D frag: col = lane&15, row = (lane>>4)*4 + reg   [m89-verified]
    const int rbase = (lane >> 4) << 2;
    const size_t m0 = (size_t)bx * 128;
    const int n0 = by * 128;
#pragma unroll
    for (int i = 0; i < 4; i++) {
#pragma unroll
        for (int j = 0; j < 4; j++) {
#pragma unroll
            for (int rg = 0; rg < 4; ++rg) {
                size_t m = m0 + wm * 64 + i * 16 + rbase + rg;
                int n = n0 + wn * 64 + j * 16 + fr;
                float v = acc[i][j][rg];
                if constexpr (EPI == 0) {
                    float v0 = v + bias[n];
#pragma unroll
                    for (int d = 0; d < 4; ++d) {
                        float u = v0 + chan[d * 512 + n];
                        out[(m * 4 + d) * 512 + n] = f2bf(leaky(u));
                    }
                } else if constexpr (EPI == 1 || EPI == 2 || EPI == 3) {
                    int d = (int)(m & 3);
                    float u = v + bias[n] + chan[d * 512 + n];
                    if constexpr (EPI == 2) u += bf2f(resid[(m >> 2) * 512 + n]);
                    out[m * 512 + n] = f2bf(EPI == 3 ? u : leaky(u));
                } else {
                    float u = v + bias[n];
                    out[m * 512 + n] = f2bf(EPI == 4 ? leaky(u) : u);
                }
            }
        }
    }
}

// ---------------- final: out[64000][2] ----------------
__global__ __launch_bounds__(256) void final_k(
    const unsigned short* __restrict__ A, const float* __restrict__ outW,
    const float* __restrict__ outb, float* __restrict__ out) {
    int gw = blockIdx.x * 4 + (threadIdx.x >> 6);
    int lane = threadIdx.x & 63;
    const unsigned short* row = A + (size_t)gw * 512;
    uint4 bits = *(const uint4*)(row + lane * 8);
    unsigned int ww[4] = {bits.x, bits.y, bits.z, bits.w};
    float s0 = 0.f, s1 = 0.f;
#pragma unroll
    for (int j = 0; j < 8; j++) {
        unsigned short u = (unsigned short)((ww[j >> 1] >> ((j & 1) * 16)) & 0xffff);
        float a = bf2f(u);
        int k = lane * 8 + j;
        s0 = fmaf(a, outW[k * 2 + 0], s0);
        s1 = fmaf(a, outW[k * 2 + 1], s1);
    }
    for (int o = 32; o; o >>= 1) {
        s0 += __shfl_down(s0, o);
        s1 += __shfl_down(s1, o);
    }
    if (lane == 0) {
        out[(size_t)gw * 2 + 0] = s0 + outb[0];
        out[(size_t)gw * 2 + 1] = s1 + outb[1];
    }
}

extern "C" void kernel_launch(void* const* d_in, const int* in_sizes, int n_in,
                              void* d_out, int out_size, void* d_ws, size_t ws_size,
                              hipStream_t stream) {
    const float* input_stuff = (const float*)d_in[0];
    const float* sound_loc   = (const float*)d_in[1];
    const float* grid_xy     = (const float*)d_in[2];
    const float* xy_offset   = (const float*)d_in[3];
    const float* bandwidths  = (const float*)d_in[4];
    const float* grid_0      = (const float*)d_in[5];
    const float* proj_W      = (const float*)d_in[6];
    const float* proj_b      = (const float*)d_in[7];
    const float* res_W0      = (const float*)d_in[8];
    const float* res_b0      = (const float*)d_in[9];
    const float* res_W1      = (const float*)d_in[10];
    const float* res_b1      = (const float*)d_in[11];
    const float* layers_W    = (const float*)d_in[12];
    const float* layers_b    = (const float*)d_in[13];
    const float* channels    = (const float*)d_in[14];
    const float* out_W       = (const float*)d_in[15];
    const float* out_b       = (const float*)d_in[16];

    char* ws = (char*)d_ws;
    float* feats            = (float*)(ws + OFF_FEATS);
    unsigned short* projWT  = (unsigned short*)(ws + OFF_PROJWT);
    unsigned short* res0WT  = (unsigned short*)(ws + OFF_RES0WT);
    unsigned short* res1WT  = (unsigned short*)(ws + OFF_RES1WT);
    unsigned short* layWT   = (unsigned short*)(ws + OFF_LAYWT);
    unsigned short* myin    = (unsigned short*)(ws + OFF_MYIN);
    unsigned short* R0      = (unsigned short*)(ws + OFF_R0);
    unsigned short* Rb      = (unsigned short*)(ws + OFF_R);
    unsigned short* A0      = (unsigned short*)(ws + OFF_A0);
    unsigned short* A1      = (unsigned short*)(ws + OFF_A1);
    float* partial          = (float*)(ws + OFF_A0);

    wconv_k<<<(512 * 256 + 255) / 256, 256, 0, stream>>>(proj_W, projWT, CATCH, CATPAD, IC, 512 * 256);
    wconv_k<<<(512 * 256 + 255) / 256, 256, 0, stream>>>(res_W0, res0WT, CATCH, CATPAD, IC, 512 * 256);
    wconv_k<<<(512 * 512 + 255) / 256, 256, 0, stream>>>(res_W1, res1WT, IC, IC, IC, 512 * 512);
    wconv_k<<<(6 * 512 * 512 + 255) / 256, 256, 0, stream>>>(layers_W, layWT, IC, IC, IC, 6 * 512 * 512);

    feats_part_k<<<dim3(16, NSLICE), 256, 0, stream>>>(grid_xy, xy_offset, bandwidths, grid_0, sound_loc, partial);
    feats_reduce_k<<<16, 128, 0, stream>>>(partial, feats);
    build_k<<<MROWS, 256, 0, stream>>>(feats, input_stuff, myin);

    // proj (+channels[0], leaky, expand x4) -> A0
    gemm_k<0><<<500, 256, 0, stream>>>(myin, projWT, A0, CATPAD, proj_b, channels, nullptr);
    // residual branch
    gemm_k<4><<<500, 256, 0, stream>>>(myin, res0WT, R0, CATPAD, res_b0, nullptr, nullptr);
    gemm_k<5><<<500, 256, 0, stream>>>(R0, res1WT, Rb, IC, res_b1, nullptr, nullptr);
    // 6 layers, ping-pong A0/A1; residual at k==2; k==5 last (no leaky)
    gemm_k<1><<<2000, 256, 0, stream>>>(A0, layWT + 0 * 262144, A1, IC, layers_b + 0 * 512, channels + 1 * 2048, nullptr);
    gemm_k<1><<<2000, 256, 0, stream>>>(A1, layWT + 1 * 262144, A0, IC, layers_b + 1 * 512, channels + 2 * 2048, nullptr);
    gemm_k<2><<<2000, 256, 0, stream>>>(A0, layWT + 2 * 262144, A1, IC, layers_b + 2 * 512, channels + 3 * 2048, Rb);
    gemm_k<1><<<2000, 256, 0, stream>>>(A1, layWT + 3 * 262144, A0, IC, layers_b + 3 * 512, channels + 4 * 2048, nullptr);
    gemm_k<1><<<2000, 256, 0, stream>>>(A0, layWT + 4 * 262144, A1, IC, layers_b + 4 * 512, channels + 5 * 2048, nullptr);
    gemm_k<3><<<2000, 256, 0, stream>>>(A1, layWT + 5 * 262144, A0, IC, layers_b + 5 * 512, channels + 6 * 2048, nullptr);

    final_k<<<MROWS, 256, 0, stream>>>(A0, out_W, out_b, (float*)d_out);
}